// Round 2
// baseline (1724.607 us; speedup 1.0000x reference)
//
#include <hip/hip_runtime.h>
#include <math.h>

#define NUM_NODES 50000
#define NUM_EDGES 1600000
#define DIM 128
#define EDGE_DIM 16
#define NKT1 18           // k-tiles (16) for GEMM1 (K=272 padded to 288)
#define NKT2 8            // k-tiles (16) for GEMM2
#define MT 128            // edges per tile
#define ROWSTRIDE 296     // shorts per x-row in LDS
#define CSTRIDE 129       // floats per C-row in LDS (conflict-free)
#define NSCAN 196         // ceil(50000/256)

typedef short bf16x8 __attribute__((ext_vector_type(8)));
typedef float floatx16 __attribute__((ext_vector_type(16)));
typedef unsigned short ushort4v __attribute__((ext_vector_type(4)));

__device__ __forceinline__ unsigned short f2b(float f) {
    unsigned u = __builtin_bit_cast(unsigned, f);
    u += 0x7FFFu + ((u >> 16) & 1u);   // round-to-nearest-even
    return (unsigned short)(u >> 16);
}

// ---- Repack W1/W2 (fp32 [K][N]) -> bf16 MFMA B-fragment order -----------
__global__ void prep_kernel(const float* __restrict__ W1, const float* __restrict__ W2,
                            short* __restrict__ W1f, short* __restrict__ W2f)
{
    int gid = blockIdx.x * 256 + threadIdx.x;
    if (gid < NKT1 * 4 * 64) {
        int lane = gid & 63, nb = (gid >> 6) & 3, kt = gid >> 8;
        int n = nb * 32 + (lane & 31);
        int kbase = kt * 16 + (lane >> 5) * 8;
        #pragma unroll
        for (int j = 0; j < 8; ++j) {
            int k = kbase + j;
            W1f[gid * 8 + j] = (k < 272) ? (short)f2b(W1[(size_t)k * DIM + n]) : (short)0;
        }
    } else if (gid < NKT1 * 4 * 64 + NKT2 * 4 * 64) {
        int g2 = gid - NKT1 * 4 * 64;
        int lane = g2 & 63, nb = (g2 >> 6) & 3, kt = g2 >> 8;
        int n = nb * 32 + (lane & 31);
        int kbase = kt * 16 + (lane >> 5) * 8;
        #pragma unroll
        for (int j = 0; j < 8; ++j)
            W2f[g2 * 8 + j] = (short)f2b(W2[(size_t)(kbase + j) * DIM + n]);
    }
}

// ---- counting sort of edges by dst --------------------------------------
__global__ void hist_kernel(const int* __restrict__ dst, int* __restrict__ counts) {
    int e = blockIdx.x * 256 + threadIdx.x;
    atomicAdd(&counts[dst[e]], 1);
}

__global__ void scanA_kernel(const int* __restrict__ counts, int* __restrict__ bsum) {
    __shared__ int sb[256];
    int t = threadIdx.x, i = blockIdx.x * 256 + t;
    int v = (i < NUM_NODES) ? counts[i] : 0;
    sb[t] = v; __syncthreads();
    for (int off = 1; off < 256; off <<= 1) {
        int x = (t >= off) ? sb[t - off] : 0;
        __syncthreads(); sb[t] += x; __syncthreads();
    }
    if (t == 255) bsum[blockIdx.x] = sb[255];
}

__global__ void scanB_kernel(const int* __restrict__ bsum, int* __restrict__ boffs) {
    __shared__ int sb[256];
    int t = threadIdx.x;
    int v = (t < NSCAN) ? bsum[t] : 0;
    sb[t] = v; __syncthreads();
    for (int off = 1; off < 256; off <<= 1) {
        int x = (t >= off) ? sb[t - off] : 0;
        __syncthreads(); sb[t] += x; __syncthreads();
    }
    if (t < NSCAN) boffs[t] = sb[t] - v;   // exclusive
}

__global__ void scanC_kernel(const int* __restrict__ counts, const int* __restrict__ boffs,
                             int* __restrict__ cursor) {
    __shared__ int sb[256];
    int t = threadIdx.x, i = blockIdx.x * 256 + t;
    int v = (i < NUM_NODES) ? counts[i] : 0;
    sb[t] = v; __syncthreads();
    for (int off = 1; off < 256; off <<= 1) {
        int x = (t >= off) ? sb[t - off] : 0;
        __syncthreads(); sb[t] += x; __syncthreads();
    }
    if (i < NUM_NODES) cursor[i] = boffs[blockIdx.x] + sb[t] - v;  // exclusive offset
}

__global__ void scatter_kernel(const int* __restrict__ dst, int* __restrict__ cursor,
                               int* __restrict__ perm) {
    int e = blockIdx.x * 256 + threadIdx.x;
    int d = dst[e];
    int p = atomicAdd(&cursor[d], 1);
    perm[p] = e;
}

// ---- Fused edge MLP on dst-sorted edges ---------------------------------
__global__ __launch_bounds__(256, 2) void edge_sorted_kernel(
    const float* __restrict__ h, const int* __restrict__ src, const int* __restrict__ dst,
    const float* __restrict__ ea, const int* __restrict__ perm,
    const short* __restrict__ W1f, const short* __restrict__ W2f,
    const float* __restrict__ pb1, const float* __restrict__ pb2, float* __restrict__ agg)
{
    __shared__ __align__(16) short xbuf[MT * ROWSTRIDE];   // 75776 B (>= 128*129*4 = 66048)
    __shared__ int eidl[MT];
    __shared__ int srcl[MT];
    __shared__ int dstl[MT];
    short* hdnf = xbuf;                  // hdn A-fragments overlay (32768 B)
    float* cbuf = (float*)xbuf;          // C fp32 overlay (66048 B)

    const int tid = threadIdx.x;
    const long long base = (long long)blockIdx.x * MT;

    if (tid < MT) { int e = perm[base + tid];      eidl[tid] = e;      srcl[tid] = src[e]; }
    else          { int e = perm[base + tid - MT]; dstl[tid - MT] = dst[e]; }
    __syncthreads();

    // gather + fp32->bf16: 128 rows x 74 chunks of 4 floats; chunks >= 68 zero-pad
    for (int it = 0; it < 37; ++it) {
        int i = tid + it * 256;
        int row = i / 74, c = i - row * 74;
        float4 v = make_float4(0.f, 0.f, 0.f, 0.f);
        if (c < 32)      v = *(const float4*)(h + (size_t)srcl[row] * DIM + c * 4);
        else if (c < 64) v = *(const float4*)(h + (size_t)dstl[row] * DIM + (c - 32) * 4);
        else if (c < 68) v = *(const float4*)(ea + (size_t)eidl[row] * EDGE_DIM + (c - 64) * 4);
        ushort4v o;
        o.x = f2b(v.x); o.y = f2b(v.y); o.z = f2b(v.z); o.w = f2b(v.w);
        *(ushort4v*)&xbuf[row * ROWSTRIDE + c * 4] = o;
    }
    __syncthreads();

    const int lane = tid & 63, wave = tid >> 6;
    const int rm = wave >> 1, rn = wave & 1;
    const int lm = lane & 31, half = lane >> 5;

    // ---------------- GEMM1 ----------------
    floatx16 acc[2][2] = {};
    #pragma unroll
    for (int kt = 0; kt < NKT1; ++kt) {
        bf16x8 a0 = *(const bf16x8*)&xbuf[(rm * 64 + lm) * ROWSTRIDE + kt * 16 + half * 8];
        bf16x8 a1 = *(const bf16x8*)&xbuf[(rm * 64 + 32 + lm) * ROWSTRIDE + kt * 16 + half * 8];
        bf16x8 b0 = *(const bf16x8*)(W1f + ((kt * 4 + rn * 2 + 0) * 64 + lane) * 8);
        bf16x8 b1 = *(const bf16x8*)(W1f + ((kt * 4 + rn * 2 + 1) * 64 + lane) * 8);
        acc[0][0] = __builtin_amdgcn_mfma_f32_32x32x16_bf16(a0, b0, acc[0][0], 0, 0, 0);
        acc[0][1] = __builtin_amdgcn_mfma_f32_32x32x16_bf16(a0, b1, acc[0][1], 0, 0, 0);
        acc[1][0] = __builtin_amdgcn_mfma_f32_32x32x16_bf16(a1, b0, acc[1][0], 0, 0, 0);
        acc[1][1] = __builtin_amdgcn_mfma_f32_32x32x16_bf16(a1, b1, acc[1][1], 0, 0, 0);
    }
    __syncthreads();

    // ---------------- bias + GELU (tanh form) -> hdn A-fragments ----------
    float bb1_0 = pb1[rn * 64 + lm];
    float bb1_1 = pb1[rn * 64 + 32 + lm];
    #pragma unroll
    for (int i = 0; i < 2; ++i) {
        #pragma unroll
        for (int j = 0; j < 2; ++j) {
            float bb = j ? bb1_1 : bb1_0;
            int kg = rn * 64 + j * 32 + lm;
            int ktl = kg >> 4;
            int lrbase = 32 * ((lm >> 3) & 1);
            int jr = lm & 7;
            #pragma unroll
            for (int r = 0; r < 16; ++r) {
                int rr = (r & 3) + 8 * (r >> 2) + 4 * half;
                float v = acc[i][j][r] + bb;
                // gelu(v) = v * t/(t+1), t = exp(2*0.7978845608*(v + 0.044715 v^3))
                float u = v * (1.5957691216f + 0.0713548163f * v * v);
                u = fminf(u, 80.f);
                float t = __expf(u);
                float g = v * t * __frcp_rn(t + 1.f);
                hdnf[(((rm * 2 + i) * 8 + ktl) * 64 + rr + lrbase) * 8 + jr] = (short)f2b(g);
            }
        }
    }
    __syncthreads();

    // ---------------- GEMM2 ----------------
    floatx16 acc2[2][2] = {};
    #pragma unroll
    for (int kt = 0; kt < NKT2; ++kt) {
        bf16x8 a0 = *(const bf16x8*)&hdnf[(((rm * 2 + 0) * 8 + kt) * 64 + lane) * 8];
        bf16x8 a1 = *(const bf16x8*)&hdnf[(((rm * 2 + 1) * 8 + kt) * 64 + lane) * 8];
        bf16x8 b0 = *(const bf16x8*)(W2f + ((kt * 4 + rn * 2 + 0) * 64 + lane) * 8);
        bf16x8 b1 = *(const bf16x8*)(W2f + ((kt * 4 + rn * 2 + 1) * 64 + lane) * 8);
        acc2[0][0] = __builtin_amdgcn_mfma_f32_32x32x16_bf16(a0, b0, acc2[0][0], 0, 0, 0);
        acc2[0][1] = __builtin_amdgcn_mfma_f32_32x32x16_bf16(a0, b1, acc2[0][1], 0, 0, 0);
        acc2[1][0] = __builtin_amdgcn_mfma_f32_32x32x16_bf16(a1, b0, acc2[1][0], 0, 0, 0);
        acc2[1][1] = __builtin_amdgcn_mfma_f32_32x32x16_bf16(a1, b1, acc2[1][1], 0, 0, 0);
    }
    __syncthreads();   // hdnf reads done before cbuf overlay

    // ---------------- bias -> C in LDS (fp32) ----------------
    float bb2_0 = pb2[rn * 64 + lm];
    float bb2_1 = pb2[rn * 64 + 32 + lm];
    #pragma unroll
    for (int i = 0; i < 2; ++i) {
        #pragma unroll
        for (int j = 0; j < 2; ++j) {
            float bb = j ? bb2_1 : bb2_0;
            int col = rn * 64 + j * 32 + lm;
            #pragma unroll
            for (int r = 0; r < 16; ++r) {
                int rr = (r & 3) + 8 * (r >> 2) + 4 * half;
                cbuf[(rm * 64 + i * 32 + rr) * CSTRIDE + col] = acc2[i][j][r] + bb;
            }
        }
    }
    __syncthreads();

    // ---------------- segmented column-sum + one atomic per segment -------
    // dstl[] is nondecreasing (globally sorted slice). Wave-uniform branches.
    {
        int col = tid & 127, whichHalf = tid >> 7;
        int r0 = whichHalf * 64, r1 = r0 + 64;
        float s = 0.f;
        int cur = dstl[r0];
        for (int r = r0; r < r1; ++r) {
            s += cbuf[r * CSTRIDE + col];
            int nxt = (r == r1 - 1) ? -1 : dstl[r + 1];
            if (nxt != cur) {
                atomicAdd(&agg[(size_t)cur * DIM + col], s);
                s = 0.f;
                cur = nxt;
            }
        }
    }
}

// ---- fallback: original per-lane atomic epilogue (if ws too small) ------
__global__ __launch_bounds__(256, 2) void edge_atomic_kernel(
    const float* __restrict__ h, const int* __restrict__ src, const int* __restrict__ dst,
    const float* __restrict__ ea, const short* __restrict__ W1f, const short* __restrict__ W2f,
    const float* __restrict__ pb1, const float* __restrict__ pb2, float* __restrict__ agg)
{
    __shared__ __align__(16) short xbuf[MT * ROWSTRIDE];
    __shared__ int srcl[MT];
    __shared__ int dstl[MT];
    short* hdnf = xbuf;

    const int tid = threadIdx.x;
    const long long base = (long long)blockIdx.x * MT;
    if (tid < MT) srcl[tid] = src[base + tid];
    else          dstl[tid - MT] = dst[base + (tid - MT)];
    __syncthreads();
    for (int it = 0; it < 37; ++it) {
        int i = tid + it * 256;
        int row = i / 74, c = i - row * 74;
        float4 v = make_float4(0.f, 0.f, 0.f, 0.f);
        if (c < 32)      v = *(const float4*)(h + (size_t)srcl[row] * DIM + c * 4);
        else if (c < 64) v = *(const float4*)(h + (size_t)dstl[row] * DIM + (c - 32) * 4);
        else if (c < 68) v = *(const float4*)(ea + (size_t)(base + row) * EDGE_DIM + (c - 64) * 4);
        ushort4v o;
        o.x = f2b(v.x); o.y = f2b(v.y); o.z = f2b(v.z); o.w = f2b(v.w);
        *(ushort4v*)&xbuf[row * ROWSTRIDE + c * 4] = o;
    }
    __syncthreads();
    const int lane = tid & 63, wave = tid >> 6;
    const int rm = wave >> 1, rn = wave & 1;
    const int lm = lane & 31, half = lane >> 5;
    floatx16 acc[2][2] = {};
    #pragma unroll
    for (int kt = 0; kt < NKT1; ++kt) {
        bf16x8 a0 = *(const bf16x8*)&xbuf[(rm * 64 + lm) * ROWSTRIDE + kt * 16 + half * 8];
        bf16x8 a1 = *(const bf16x8*)&xbuf[(rm * 64 + 32 + lm) * ROWSTRIDE + kt * 16 + half * 8];
        bf16x8 b0 = *(const bf16x8*)(W1f + ((kt * 4 + rn * 2 + 0) * 64 + lane) * 8);
        bf16x8 b1 = *(const bf16x8*)(W1f + ((kt * 4 + rn * 2 + 1) * 64 + lane) * 8);
        acc[0][0] = __builtin_amdgcn_mfma_f32_32x32x16_bf16(a0, b0, acc[0][0], 0, 0, 0);
        acc[0][1] = __builtin_amdgcn_mfma_f32_32x32x16_bf16(a0, b1, acc[0][1], 0, 0, 0);
        acc[1][0] = __builtin_amdgcn_mfma_f32_32x32x16_bf16(a1, b0, acc[1][0], 0, 0, 0);
        acc[1][1] = __builtin_amdgcn_mfma_f32_32x32x16_bf16(a1, b1, acc[1][1], 0, 0, 0);
    }
    __syncthreads();
    float bb1_0 = pb1[rn * 64 + lm];
    float bb1_1 = pb1[rn * 64 + 32 + lm];
    #pragma unroll
    for (int i = 0; i < 2; ++i)
        #pragma unroll
        for (int j = 0; j < 2; ++j) {
            float bb = j ? bb1_1 : bb1_0;
            int kg = rn * 64 + j * 32 + lm;
            int ktl = kg >> 4;
            int lrbase = 32 * ((lm >> 3) & 1);
            int jr = lm & 7;
            #pragma unroll
            for (int r = 0; r < 16; ++r) {
                int rr = (r & 3) + 8 * (r >> 2) + 4 * half;
                float v = acc[i][j][r] + bb;
                float u = v * (1.5957691216f + 0.0713548163f * v * v);
                u = fminf(u, 80.f);
                float t = __expf(u);
                float g = v * t * __frcp_rn(t + 1.f);
                hdnf[(((rm * 2 + i) * 8 + ktl) * 64 + rr + lrbase) * 8 + jr] = (short)f2b(g);
            }
        }
    __syncthreads();
    floatx16 acc2[2][2] = {};
    #pragma unroll
    for (int kt = 0; kt < NKT2; ++kt) {
        bf16x8 a0 = *(const bf16x8*)&hdnf[(((rm * 2 + 0) * 8 + kt) * 64 + lane) * 8];
        bf16x8 a1 = *(const bf16x8*)&hdnf[(((rm * 2 + 1) * 8 + kt) * 64 + lane) * 8];
        bf16x8 b0 = *(const bf16x8*)(W2f + ((kt * 4 + rn * 2 + 0) * 64 + lane) * 8);
        bf16x8 b1 = *(const bf16x8*)(W2f + ((kt * 4 + rn * 2 + 1) * 64 + lane) * 8);
        acc2[0][0] = __builtin_amdgcn_mfma_f32_32x32x16_bf16(a0, b0, acc2[0][0], 0, 0, 0);
        acc2[0][1] = __builtin_amdgcn_mfma_f32_32x32x16_bf16(a0, b1, acc2[0][1], 0, 0, 0);
        acc2[1][0] = __builtin_amdgcn_mfma_f32_32x32x16_bf16(a1, b0, acc2[1][0], 0, 0, 0);
        acc2[1][1] = __builtin_amdgcn_mfma_f32_32x32x16_bf16(a1, b1, acc2[1][1], 0, 0, 0);
    }
    float bb2_0 = pb2[rn * 64 + lm];
    float bb2_1 = pb2[rn * 64 + 32 + lm];
    #pragma unroll
    for (int i = 0; i < 2; ++i)
        #pragma unroll
        for (int j = 0; j < 2; ++j) {
            float bb = j ? bb2_1 : bb2_0;
            int n = rn * 64 + j * 32 + lm;
            #pragma unroll
            for (int r = 0; r < 16; ++r) {
                int rr = (r & 3) + 8 * (r >> 2) + 4 * half;
                int erow = rm * 64 + i * 32 + rr;
                atomicAdd(&agg[(size_t)dstl[erow] * DIM + n], acc2[i][j][r] + bb);
            }
        }
}

// ---- LayerNorm over h + agg (in place on agg = d_out) -------------------
__global__ __launch_bounds__(256) void ln_kernel(
    const float* __restrict__ h, float* __restrict__ io,
    const float* __restrict__ gamma, const float* __restrict__ beta)
{
    int wave = threadIdx.x >> 6, lane = threadIdx.x & 63;
    int node = blockIdx.x * 4 + wave;
    const float2* h2 = (const float2*)(h + (size_t)node * DIM);
    float2* o2 = (float2*)(io + (size_t)node * DIM);
    float2 a = o2[lane];
    float2 b = h2[lane];
    float x0 = a.x + b.x, x1 = a.y + b.y;
    float s = x0 + x1;
    float ss = x0 * x0 + x1 * x1;
    #pragma unroll
    for (int m = 1; m < 64; m <<= 1) {
        s  += __shfl_xor(s, m, 64);
        ss += __shfl_xor(ss, m, 64);
    }
    float mu = s * (1.f / DIM);
    float var = ss * (1.f / DIM) - mu * mu;
    float rs = rsqrtf(var + 1e-5f);
    float g0 = gamma[lane * 2], g1 = gamma[lane * 2 + 1];
    float e0 = beta[lane * 2],  e1 = beta[lane * 2 + 1];
    float2 outv;
    outv.x = (x0 - mu) * rs * g0 + e0;
    outv.y = (x1 - mu) * rs * g1 + e1;
    o2[lane] = outv;
}

extern "C" void kernel_launch(void* const* d_in, const int* in_sizes, int n_in,
                              void* d_out, int out_size, void* d_ws, size_t ws_size,
                              hipStream_t stream)
{
    const float* h     = (const float*)d_in[0];
    const int*   src   = (const int*)d_in[1];
    const int*   dst   = (const int*)d_in[2];
    const float* ea    = (const float*)d_in[3];
    const float* W1    = (const float*)d_in[4];
    const float* pb1   = (const float*)d_in[5];
    const float* W2    = (const float*)d_in[6];
    const float* pb2   = (const float*)d_in[7];
    const float* gamma = (const float*)d_in[8];
    const float* beta  = (const float*)d_in[9];
    float* out = (float*)d_out;

    char* ws = (char*)d_ws;
    short* W1f   = (short*)ws;                       //      0 .. 73728
    short* W2f   = (short*)(ws + 73728);             //  73728 .. 106496
    int* counts  = (int*)(ws + 106496);              // 200000 B
    int* cursor  = (int*)(ws + 306496);              // 200000 B
    int* bsum    = (int*)(ws + 506496);              //   1024 B
    int* boffs   = (int*)(ws + 507520);              //   1024 B
    int* perm    = (int*)(ws + 508544);              // 6400000 B
    const size_t REQUIRED = 508544 + (size_t)NUM_EDGES * 4;

    hipMemsetAsync(d_out, 0, (size_t)NUM_NODES * DIM * sizeof(float), stream);
    prep_kernel<<<26, 256, 0, stream>>>(W1, W2, W1f, W2f);

    if (ws_size >= REQUIRED) {
        hipMemsetAsync(counts, 0, NUM_NODES * sizeof(int), stream);
        hist_kernel<<<NUM_EDGES / 256, 256, 0, stream>>>(dst, counts);
        scanA_kernel<<<NSCAN, 256, 0, stream>>>(counts, bsum);
        scanB_kernel<<<1, 256, 0, stream>>>(bsum, boffs);
        scanC_kernel<<<NSCAN, 256, 0, stream>>>(counts, boffs, cursor);
        scatter_kernel<<<NUM_EDGES / 256, 256, 0, stream>>>(dst, cursor, perm);
        edge_sorted_kernel<<<NUM_EDGES / MT, 256, 0, stream>>>(
            h, src, dst, ea, perm, W1f, W2f, pb1, pb2, out);
    } else {
        edge_atomic_kernel<<<NUM_EDGES / MT, 256, 0, stream>>>(
            h, src, dst, ea, W1f, W2f, pb1, pb2, out);
    }
    ln_kernel<<<NUM_NODES / 4, 256, 0, stream>>>(h, out, gamma, beta);
}

// Round 3
// 678.572 us; speedup vs baseline: 2.5415x; 2.5415x over previous
//
#include <hip/hip_runtime.h>
#include <math.h>

#define NUM_NODES 50000
#define NUM_EDGES 1600000
#define DIM 128
#define EDGE_DIM 16
#define NKT1 18           // k-tiles (16) for GEMM1 (K=272 padded to 288)
#define NKT2 8            // k-tiles (16) for GEMM2
#define MT 64             // edges per tile (sorted kernel)
#define XSTRIDE 296       // shorts per x-row in LDS (592 B)
#define CSTRIDE 132       // floats per C-row in LDS
#define NSCAN 196         // ceil(50000/256)

typedef short bf16x8 __attribute__((ext_vector_type(8)));
typedef float floatx16 __attribute__((ext_vector_type(16)));
typedef unsigned short ushort4v __attribute__((ext_vector_type(4)));
typedef unsigned short ushort8v __attribute__((ext_vector_type(8)));

__device__ __forceinline__ unsigned short f2b(float f) {
    unsigned u = __builtin_bit_cast(unsigned, f);
    u += 0x7FFFu + ((u >> 16) & 1u);   // round-to-nearest-even
    return (unsigned short)(u >> 16);
}

// ---- Repack W1/W2 (fp32 [K][N]) -> bf16 MFMA B-fragment order -----------
__global__ void prep_kernel(const float* __restrict__ W1, const float* __restrict__ W2,
                            short* __restrict__ W1f, short* __restrict__ W2f)
{
    int gid = blockIdx.x * 256 + threadIdx.x;
    if (gid < NKT1 * 4 * 64) {
        int lane = gid & 63, nb = (gid >> 6) & 3, kt = gid >> 8;
        int n = nb * 32 + (lane & 31);
        int kbase = kt * 16 + (lane >> 5) * 8;
        #pragma unroll
        for (int j = 0; j < 8; ++j) {
            int k = kbase + j;
            W1f[gid * 8 + j] = (k < 272) ? (short)f2b(W1[(size_t)k * DIM + n]) : (short)0;
        }
    } else if (gid < NKT1 * 4 * 64 + NKT2 * 4 * 64) {
        int g2 = gid - NKT1 * 4 * 64;
        int lane = g2 & 63, nb = (g2 >> 6) & 3, kt = g2 >> 8;
        int n = nb * 32 + (lane & 31);
        int kbase = kt * 16 + (lane >> 5) * 8;
        #pragma unroll
        for (int j = 0; j < 8; ++j)
            W2f[g2 * 8 + j] = (short)f2b(W2[(size_t)(kbase + j) * DIM + n]);
    }
}

// ---- h fp32 -> bf16 ----------------------------------------------------
__global__ void hconv_kernel(const float* __restrict__ h, unsigned short* __restrict__ h_bf) {
    int t = blockIdx.x * 256 + threadIdx.x;   // covers 4 floats each
    float4 v = ((const float4*)h)[t];
    ushort4v o;
    o.x = f2b(v.x); o.y = f2b(v.y); o.z = f2b(v.z); o.w = f2b(v.w);
    ((ushort4v*)h_bf)[t] = o;
}

// ---- counting sort of edges by dst --------------------------------------
__global__ void hist_kernel(const int* __restrict__ dst, int* __restrict__ counts) {
    int e = blockIdx.x * 256 + threadIdx.x;
    atomicAdd(&counts[dst[e]], 1);
}

__global__ void scanA_kernel(const int* __restrict__ counts, int* __restrict__ bsum) {
    __shared__ int sb[256];
    int t = threadIdx.x, i = blockIdx.x * 256 + t;
    int v = (i < NUM_NODES) ? counts[i] : 0;
    sb[t] = v; __syncthreads();
    for (int off = 1; off < 256; off <<= 1) {
        int x = (t >= off) ? sb[t - off] : 0;
        __syncthreads(); sb[t] += x; __syncthreads();
    }
    if (t == 255) bsum[blockIdx.x] = sb[255];
}

__global__ void scanB_kernel(const int* __restrict__ bsum, int* __restrict__ boffs) {
    __shared__ int sb[256];
    int t = threadIdx.x;
    int v = (t < NSCAN) ? bsum[t] : 0;
    sb[t] = v; __syncthreads();
    for (int off = 1; off < 256; off <<= 1) {
        int x = (t >= off) ? sb[t - off] : 0;
        __syncthreads(); sb[t] += x; __syncthreads();
    }
    if (t < NSCAN) boffs[t] = sb[t] - v;   // exclusive
}

__global__ void scanC_kernel(const int* __restrict__ counts, const int* __restrict__ boffs,
                             int* __restrict__ cursor) {
    __shared__ int sb[256];
    int t = threadIdx.x, i = blockIdx.x * 256 + t;
    int v = (i < NUM_NODES) ? counts[i] : 0;
    sb[t] = v; __syncthreads();
    for (int off = 1; off < 256; off <<= 1) {
        int x = (t >= off) ? sb[t - off] : 0;
        __syncthreads(); sb[t] += x; __syncthreads();
    }
    if (i < NUM_NODES) cursor[i] = boffs[blockIdx.x] + sb[t] - v;  // exclusive offset
}

// ---- scatter to sorted order; emit src_s/dst_s and bf16 ea_s ------------
__global__ void scatter2_kernel(const int* __restrict__ src, const int* __restrict__ dst,
                                const float* __restrict__ ea, int* __restrict__ cursor,
                                int* __restrict__ src_s, int* __restrict__ dst_s,
                                unsigned short* __restrict__ ea_s)
{
    int e = blockIdx.x * 256 + threadIdx.x;
    int d = dst[e];
    int p = atomicAdd(&cursor[d], 1);
    src_s[p] = src[e];
    dst_s[p] = d;
    const float4* er = (const float4*)(ea + (size_t)e * EDGE_DIM);
    __attribute__((aligned(16))) unsigned short tmp[16];
    #pragma unroll
    for (int c = 0; c < 4; ++c) {
        float4 v = er[c];
        tmp[c * 4 + 0] = f2b(v.x); tmp[c * 4 + 1] = f2b(v.y);
        tmp[c * 4 + 2] = f2b(v.z); tmp[c * 4 + 3] = f2b(v.w);
    }
    ushort8v* o = (ushort8v*)(ea_s + (size_t)p * EDGE_DIM);
    o[0] = *(ushort8v*)&tmp[0];
    o[1] = *(ushort8v*)&tmp[8];
}

// ---- Fused edge MLP on dst-sorted, pre-bf16 inputs ----------------------
__global__ __launch_bounds__(256, 4) void edge_sorted_kernel(
    const unsigned short* __restrict__ h_bf,
    const int* __restrict__ src_s, const int* __restrict__ dst_s,
    const unsigned short* __restrict__ ea_s,
    const short* __restrict__ W1f, const short* __restrict__ W2f,
    const float* __restrict__ pb1, const float* __restrict__ pb2,
    float* __restrict__ agg)
{
    __shared__ __align__(16) short xbuf[MT * XSTRIDE];   // 37888 B
    __shared__ int srcl[MT];
    __shared__ int dstl[MT];
    short* hdnf = xbuf;                  // hdn A-fragments overlay (16384 B)
    float* cbuf = (float*)xbuf;          // C fp32 overlay (33792 B)

    const int tid = threadIdx.x;
    const long long base = (long long)blockIdx.x * MT;

    if (tid < MT)            srcl[tid]      = src_s[base + tid];
    else if (tid < 2 * MT)   dstl[tid - MT] = dst_s[base + tid - MT];
    __syncthreads();

    // stage h rows (bf16, 16B chunks): 64 rows x 32 chunks, 8 iters of 256
    #pragma unroll
    for (int it = 0; it < 8; ++it) {
        int g = it * 256 + tid;
        int row = g >> 5, c = g & 31;
        const ushort8v* p = (c < 16)
            ? (const ushort8v*)(h_bf + (size_t)srcl[row] * DIM + c * 8)
            : (const ushort8v*)(h_bf + (size_t)dstl[row] * DIM + (c - 16) * 8);
        *(ushort8v*)&xbuf[row * XSTRIDE + c * 8] = *p;
    }
    // ea (cols 256..271) and zero-pad (cols 272..287)
    if (tid < 128) {
        int row = tid >> 1, c = tid & 1;
        *(ushort8v*)&xbuf[row * XSTRIDE + 256 + c * 8] =
            *(const ushort8v*)(ea_s + (size_t)(base + row) * EDGE_DIM + c * 8);
    } else {
        int t2 = tid - 128;
        int row = t2 >> 1, c = t2 & 1;
        ushort8v z = {0, 0, 0, 0, 0, 0, 0, 0};
        *(ushort8v*)&xbuf[row * XSTRIDE + 272 + c * 8] = z;
    }
    __syncthreads();

    const int lane = tid & 63, wave = tid >> 6;
    const int rm = wave >> 1, rn = wave & 1;     // rows 32*rm.., cols 64*rn..
    const int lm = lane & 31, half = lane >> 5;

    // ---------------- GEMM1: x[64,288] @ W1[288,128] ----------------
    floatx16 acc0 = {}, acc1 = {};
    #pragma unroll
    for (int kt = 0; kt < NKT1; ++kt) {
        bf16x8 a  = *(const bf16x8*)&xbuf[(rm * 32 + lm) * XSTRIDE + kt * 16 + half * 8];
        bf16x8 b0 = *(const bf16x8*)(W1f + ((kt * 4 + rn * 2 + 0) * 64 + lane) * 8);
        bf16x8 b1 = *(const bf16x8*)(W1f + ((kt * 4 + rn * 2 + 1) * 64 + lane) * 8);
        acc0 = __builtin_amdgcn_mfma_f32_32x32x16_bf16(a, b0, acc0, 0, 0, 0);
        acc1 = __builtin_amdgcn_mfma_f32_32x32x16_bf16(a, b1, acc1, 0, 0, 0);
    }
    __syncthreads();   // GEMM1 LDS reads done before hdnf overlay writes

    // ---------------- bias + GELU (tanh form) -> hdn A-fragments ----------
    #pragma unroll
    for (int j = 0; j < 2; ++j) {
        int kg = rn * 64 + j * 32 + lm;          // hidden col = GEMM2 k
        float bb = pb1[kg];
        int ktl = kg >> 4, lrb = 32 * ((kg >> 3) & 1), jr = kg & 7;
        const floatx16& A = j ? acc1 : acc0;
        #pragma unroll
        for (int r = 0; r < 16; ++r) {
            int rr = (r & 3) + 8 * (r >> 2) + 4 * half;   // edge row in strip
            float v = A[r] + bb;
            float u = v * (1.5957691216f + 0.0713548163f * v * v);
            u = fminf(u, 80.f);
            float t = __expf(u);
            float g = v * t * __builtin_amdgcn_rcpf(t + 1.f);
            hdnf[((rm * 8 + ktl) * 64 + rr + lrb) * 8 + jr] = (short)f2b(g);
        }
    }
    __syncthreads();

    // ---------------- GEMM2: hdn[64,128] @ W2[128,128] ----------------
    floatx16 acc2_0 = {}, acc2_1 = {};
    #pragma unroll
    for (int kt = 0; kt < NKT2; ++kt) {
        bf16x8 a  = *(const bf16x8*)&hdnf[((rm * 8 + kt) * 64 + lane) * 8];
        bf16x8 b0 = *(const bf16x8*)(W2f + ((kt * 4 + rn * 2 + 0) * 64 + lane) * 8);
        bf16x8 b1 = *(const bf16x8*)(W2f + ((kt * 4 + rn * 2 + 1) * 64 + lane) * 8);
        acc2_0 = __builtin_amdgcn_mfma_f32_32x32x16_bf16(a, b0, acc2_0, 0, 0, 0);
        acc2_1 = __builtin_amdgcn_mfma_f32_32x32x16_bf16(a, b1, acc2_1, 0, 0, 0);
    }
    __syncthreads();   // hdnf reads done before cbuf overlay

    // ---------------- bias -> C in LDS (fp32) ----------------
    #pragma unroll
    for (int j = 0; j < 2; ++j) {
        int col = rn * 64 + j * 32 + lm;
        float bb = pb2[col];
        const floatx16& A = j ? acc2_1 : acc2_0;
        #pragma unroll
        for (int r = 0; r < 16; ++r) {
            int rr = (r & 3) + 8 * (r >> 2) + 4 * half;
            cbuf[(rm * 32 + rr) * CSTRIDE + col] = A[r] + bb;
        }
    }
    __syncthreads();

    // ---------------- segmented column-sum + one atomic per segment -------
    {
        int col = tid & 127, hf = tid >> 7;
        int r0 = hf * 32, r1 = r0 + 32;
        float s = 0.f;
        int cur = dstl[r0];
        for (int r = r0; r < r1; ++r) {
            s += cbuf[r * CSTRIDE + col];
            int nxt = (r == r1 - 1) ? -1 : dstl[r + 1];
            if (nxt != cur) {
                atomicAdd(&agg[(size_t)cur * DIM + col], s);
                s = 0.f;
                cur = nxt;
            }
        }
    }
}

// ---- fallback: per-lane atomic epilogue (only if ws too small) ----------
__global__ __launch_bounds__(256, 2) void edge_atomic_kernel(
    const float* __restrict__ h, const int* __restrict__ src, const int* __restrict__ dst,
    const float* __restrict__ ea, const short* __restrict__ W1f, const short* __restrict__ W2f,
    const float* __restrict__ pb1, const float* __restrict__ pb2, float* __restrict__ agg)
{
    __shared__ __align__(16) short xbuf[128 * 296];
    __shared__ int srcl[128];
    __shared__ int dstl[128];
    short* hdnf = xbuf;

    const int tid = threadIdx.x;
    const long long base = (long long)blockIdx.x * 128;
    if (tid < 128) srcl[tid] = src[base + tid];
    else           dstl[tid - 128] = dst[base + (tid - 128)];
    __syncthreads();
    for (int it = 0; it < 37; ++it) {
        int i = tid + it * 256;
        int row = i / 74, c = i - row * 74;
        float4 v = make_float4(0.f, 0.f, 0.f, 0.f);
        if (c < 32)      v = *(const float4*)(h + (size_t)srcl[row] * DIM + c * 4);
        else if (c < 64) v = *(const float4*)(h + (size_t)dstl[row] * DIM + (c - 32) * 4);
        else if (c < 68) v = *(const float4*)(ea + (size_t)(base + row) * EDGE_DIM + (c - 64) * 4);
        ushort4v o;
        o.x = f2b(v.x); o.y = f2b(v.y); o.z = f2b(v.z); o.w = f2b(v.w);
        *(ushort4v*)&xbuf[row * 296 + c * 4] = o;
    }
    __syncthreads();
    const int lane = tid & 63, wave = tid >> 6;
    const int rm = wave >> 1, rn = wave & 1;
    const int lm = lane & 31, half = lane >> 5;
    floatx16 acc[2][2] = {};
    #pragma unroll
    for (int kt = 0; kt < NKT1; ++kt) {
        bf16x8 a0 = *(const bf16x8*)&xbuf[(rm * 64 + lm) * 296 + kt * 16 + half * 8];
        bf16x8 a1 = *(const bf16x8*)&xbuf[(rm * 64 + 32 + lm) * 296 + kt * 16 + half * 8];
        bf16x8 b0 = *(const bf16x8*)(W1f + ((kt * 4 + rn * 2 + 0) * 64 + lane) * 8);
        bf16x8 b1 = *(const bf16x8*)(W1f + ((kt * 4 + rn * 2 + 1) * 64 + lane) * 8);
        acc[0][0] = __builtin_amdgcn_mfma_f32_32x32x16_bf16(a0, b0, acc[0][0], 0, 0, 0);
        acc[0][1] = __builtin_amdgcn_mfma_f32_32x32x16_bf16(a0, b1, acc[0][1], 0, 0, 0);
        acc[1][0] = __builtin_amdgcn_mfma_f32_32x32x16_bf16(a1, b0, acc[1][0], 0, 0, 0);
        acc[1][1] = __builtin_amdgcn_mfma_f32_32x32x16_bf16(a1, b1, acc[1][1], 0, 0, 0);
    }
    __syncthreads();
    float bb1_0 = pb1[rn * 64 + lm];
    float bb1_1 = pb1[rn * 64 + 32 + lm];
    #pragma unroll
    for (int i = 0; i < 2; ++i)
        #pragma unroll
        for (int j = 0; j < 2; ++j) {
            float bb = j ? bb1_1 : bb1_0;
            int kg = rn * 64 + j * 32 + lm;
            int ktl = kg >> 4;
            int lrbase = 32 * ((lm >> 3) & 1);
            int jr = lm & 7;
            #pragma unroll
            for (int r = 0; r < 16; ++r) {
                int rr = (r & 3) + 8 * (r >> 2) + 4 * half;
                float v = acc[i][j][r] + bb;
                float u = v * (1.5957691216f + 0.0713548163f * v * v);
                u = fminf(u, 80.f);
                float t = __expf(u);
                float g = v * t * __builtin_amdgcn_rcpf(t + 1.f);
                hdnf[(((rm * 2 + i) * 8 + ktl) * 64 + rr + lrbase) * 8 + jr] = (short)f2b(g);
            }
        }
    __syncthreads();
    floatx16 acc2[2][2] = {};
    #pragma unroll
    for (int kt = 0; kt < NKT2; ++kt) {
        bf16x8 a0 = *(const bf16x8*)&hdnf[(((rm * 2 + 0) * 8 + kt) * 64 + lane) * 8];
        bf16x8 a1 = *(const bf16x8*)&hdnf[(((rm * 2 + 1) * 8 + kt) * 64 + lane) * 8];
        bf16x8 b0 = *(const bf16x8*)(W2f + ((kt * 4 + rn * 2 + 0) * 64 + lane) * 8);
        bf16x8 b1 = *(const bf16x8*)(W2f + ((kt * 4 + rn * 2 + 1) * 64 + lane) * 8);
        acc2[0][0] = __builtin_amdgcn_mfma_f32_32x32x16_bf16(a0, b0, acc2[0][0], 0, 0, 0);
        acc2[0][1] = __builtin_amdgcn_mfma_f32_32x32x16_bf16(a0, b1, acc2[0][1], 0, 0, 0);
        acc2[1][0] = __builtin_amdgcn_mfma_f32_32x32x16_bf16(a1, b0, acc2[1][0], 0, 0, 0);
        acc2[1][1] = __builtin_amdgcn_mfma_f32_32x32x16_bf16(a1, b1, acc2[1][1], 0, 0, 0);
    }
    float bb2_0 = pb2[rn * 64 + lm];
    float bb2_1 = pb2[rn * 64 + 32 + lm];
    #pragma unroll
    for (int i = 0; i < 2; ++i)
        #pragma unroll
        for (int j = 0; j < 2; ++j) {
            float bb = j ? bb2_1 : bb2_0;
            int n = rn * 64 + j * 32 + lm;
            #pragma unroll
            for (int r = 0; r < 16; ++r) {
                int rr = (r & 3) + 8 * (r >> 2) + 4 * half;
                atomicAdd(&agg[(size_t)dstl[rm * 64 + i * 32 + rr] * DIM + n],
                          acc2[i][j][r] + bb);
            }
        }
}

// ---- LayerNorm over h + agg (in place on agg = d_out) -------------------
__global__ __launch_bounds__(256) void ln_kernel(
    const float* __restrict__ h, float* __restrict__ io,
    const float* __restrict__ gamma, const float* __restrict__ beta)
{
    int wave = threadIdx.x >> 6, lane = threadIdx.x & 63;
    int node = blockIdx.x * 4 + wave;
    const float2* h2 = (const float2*)(h + (size_t)node * DIM);
    float2* o2 = (float2*)(io + (size_t)node * DIM);
    float2 a = o2[lane];
    float2 b = h2[lane];
    float x0 = a.x + b.x, x1 = a.y + b.y;
    float s = x0 + x1;
    float ss = x0 * x0 + x1 * x1;
    #pragma unroll
    for (int m = 1; m < 64; m <<= 1) {
        s  += __shfl_xor(s, m, 64);
        ss += __shfl_xor(ss, m, 64);
    }
    float mu = s * (1.f / DIM);
    float var = ss * (1.f / DIM) - mu * mu;
    float rs = rsqrtf(var + 1e-5f);
    float g0 = gamma[lane * 2], g1 = gamma[lane * 2 + 1];
    float e0 = beta[lane * 2],  e1 = beta[lane * 2 + 1];
    float2 outv;
    outv.x = (x0 - mu) * rs * g0 + e0;
    outv.y = (x1 - mu) * rs * g1 + e1;
    o2[lane] = outv;
}

extern "C" void kernel_launch(void* const* d_in, const int* in_sizes, int n_in,
                              void* d_out, int out_size, void* d_ws, size_t ws_size,
                              hipStream_t stream)
{
    const float* h     = (const float*)d_in[0];
    const int*   src   = (const int*)d_in[1];
    const int*   dst   = (const int*)d_in[2];
    const float* ea    = (const float*)d_in[3];
    const float* W1    = (const float*)d_in[4];
    const float* pb1   = (const float*)d_in[5];
    const float* W2    = (const float*)d_in[6];
    const float* pb2   = (const float*)d_in[7];
    const float* gamma = (const float*)d_in[8];
    const float* beta  = (const float*)d_in[9];
    float* out = (float*)d_out;

    char* ws = (char*)d_ws;
    short* W1f   = (short*)ws;                        //        0 ..    73728
    short* W2f   = (short*)(ws + 73728);              //    73728 ..   106496
    int* counts  = (int*)(ws + 106496);               //   200000 B
    int* cursor  = (int*)(ws + 306496);               //   200000 B
    int* bsum    = (int*)(ws + 506496);               //     1024 B
    int* boffs   = (int*)(ws + 507520);               //     1024 B
    int* src_s   = (int*)(ws + 508544);               //  6400000 B
    int* dst_s   = (int*)(ws + 6908544);              //  6400000 B
    unsigned short* h_bf = (unsigned short*)(ws + 13308544);   // 12800000 B
    unsigned short* ea_s = (unsigned short*)(ws + 26108544);   // 51200000 B
    const size_t REQUIRED = 77308544;

    hipMemsetAsync(d_out, 0, (size_t)NUM_NODES * DIM * sizeof(float), stream);
    prep_kernel<<<26, 256, 0, stream>>>(W1, W2, W1f, W2f);

    if (ws_size >= REQUIRED) {
        hipMemsetAsync(counts, 0, NUM_NODES * sizeof(int), stream);
        hconv_kernel<<<6250, 256, 0, stream>>>(h, h_bf);
        hist_kernel<<<NUM_EDGES / 256, 256, 0, stream>>>(dst, counts);
        scanA_kernel<<<NSCAN, 256, 0, stream>>>(counts, bsum);
        scanB_kernel<<<1, 256, 0, stream>>>(bsum, boffs);
        scanC_kernel<<<NSCAN, 256, 0, stream>>>(counts, boffs, cursor);
        scatter2_kernel<<<NUM_EDGES / 256, 256, 0, stream>>>(src, dst, ea, cursor,
                                                             src_s, dst_s, ea_s);
        edge_sorted_kernel<<<NUM_EDGES / MT, 256, 0, stream>>>(
            h_bf, src_s, dst_s, ea_s, W1f, W2f, pb1, pb2, out);
    } else {
        edge_atomic_kernel<<<NUM_EDGES / 128, 256, 0, stream>>>(
            h, src, dst, ea, W1f, W2f, pb1, pb2, out);
    }
    ln_kernel<<<NUM_NODES / 4, 256, 0, stream>>>(h, out, gamma, beta);
}

// Round 4
// 619.013 us; speedup vs baseline: 2.7861x; 1.0962x over previous
//
#include <hip/hip_runtime.h>
#include <math.h>

#define NUM_NODES 50000
#define NUM_EDGES 1600000
#define DIM 128
#define EDGE_DIM 16
#define NKT1 18           // k-tiles (16) for GEMM1 (K=272 padded to 288)
#define NKT2 8            // k-tiles (16) for GEMM2
#define MT 64             // edges per tile
#define CSTRIDE 132       // floats per C-row in LDS
#define NSCAN 196         // ceil(50000/256)
#define NODE_BLOCKS ((NUM_NODES + 63) / 64)

typedef short bf16x8 __attribute__((ext_vector_type(8)));
typedef float floatx16 __attribute__((ext_vector_type(16)));
typedef unsigned short ushort4v __attribute__((ext_vector_type(4)));
typedef unsigned short ushort8v __attribute__((ext_vector_type(8)));

__device__ __forceinline__ unsigned short f2b(float f) {
    unsigned u = __builtin_bit_cast(unsigned, f);
    u += 0x7FFFu + ((u >> 16) & 1u);   // round-to-nearest-even
    return (unsigned short)(u >> 16);
}

// ---- Repack W1/W2 (fp32 [K][N]) -> bf16 MFMA B-fragment order -----------
// [kt][nb][lane][8]: n = nb*32 + (lane&31), k = kt*16 + (lane>>5)*8 + j
__global__ void prep_kernel(const float* __restrict__ W1, const float* __restrict__ W2,
                            short* __restrict__ W1f, short* __restrict__ W2f)
{
    int gid = blockIdx.x * 256 + threadIdx.x;
    if (gid < NKT1 * 4 * 64) {
        int lane = gid & 63, nb = (gid >> 6) & 3, kt = gid >> 8;
        int n = nb * 32 + (lane & 31);
        int kbase = kt * 16 + (lane >> 5) * 8;
        #pragma unroll
        for (int j = 0; j < 8; ++j) {
            int k = kbase + j;
            W1f[gid * 8 + j] = (k < 272) ? (short)f2b(W1[(size_t)k * DIM + n]) : (short)0;
        }
    } else if (gid < NKT1 * 4 * 64 + NKT2 * 4 * 64) {
        int g2 = gid - NKT1 * 4 * 64;
        int lane = g2 & 63, nb = (g2 >> 6) & 3, kt = g2 >> 8;
        int n = nb * 32 + (lane & 31);
        int kbase = kt * 16 + (lane >> 5) * 8;
        #pragma unroll
        for (int j = 0; j < 8; ++j)
            W2f[g2 * 8 + j] = (short)f2b(W2[(size_t)(kbase + j) * DIM + n]);
    }
}

// ---- h fp32 -> bf16 ----------------------------------------------------
__global__ void hconv_kernel(const float* __restrict__ h, unsigned short* __restrict__ h_bf) {
    int t = blockIdx.x * 256 + threadIdx.x;   // 4 floats each
    float4 v = ((const float4*)h)[t];
    ushort4v o;
    o.x = f2b(v.x); o.y = f2b(v.y); o.z = f2b(v.z); o.w = f2b(v.w);
    ((ushort4v*)h_bf)[t] = o;
}

// ---- counting sort of edges by dst --------------------------------------
__global__ void hist_kernel(const int* __restrict__ dst, int* __restrict__ counts) {
    int e = blockIdx.x * 256 + threadIdx.x;
    atomicAdd(&counts[dst[e]], 1);
}

__global__ void scanA_kernel(const int* __restrict__ counts, int* __restrict__ bsum) {
    __shared__ int sb[256];
    int t = threadIdx.x, i = blockIdx.x * 256 + t;
    int v = (i < NUM_NODES) ? counts[i] : 0;
    sb[t] = v; __syncthreads();
    for (int off = 1; off < 256; off <<= 1) {
        int x = (t >= off) ? sb[t - off] : 0;
        __syncthreads(); sb[t] += x; __syncthreads();
    }
    if (t == 255) bsum[blockIdx.x] = sb[255];
}

__global__ void scanB_kernel(const int* __restrict__ bsum, int* __restrict__ boffs) {
    __shared__ int sb[256];
    int t = threadIdx.x;
    int v = (t < NSCAN) ? bsum[t] : 0;
    sb[t] = v; __syncthreads();
    for (int off = 1; off < 256; off <<= 1) {
        int x = (t >= off) ? sb[t - off] : 0;
        __syncthreads(); sb[t] += x; __syncthreads();
    }
    if (t < NSCAN) boffs[t] = sb[t] - v;   // exclusive
}

__global__ void scanC_kernel(const int* __restrict__ counts, const int* __restrict__ boffs,
                             int* __restrict__ cursor) {
    __shared__ int sb[256];
    int t = threadIdx.x, i = blockIdx.x * 256 + t;
    int v = (i < NUM_NODES) ? counts[i] : 0;
    sb[t] = v; __syncthreads();
    for (int off = 1; off < 256; off <<= 1) {
        int x = (t >= off) ? sb[t - off] : 0;
        __syncthreads(); sb[t] += x; __syncthreads();
    }
    if (i < NUM_NODES) cursor[i] = boffs[blockIdx.x] + sb[t] - v;  // exclusive offset
}

// ---- scatter edge ids/endpoints into dst-sorted order -------------------
__global__ void scatter3_kernel(const int* __restrict__ src, const int* __restrict__ dst,
                                int* __restrict__ cursor, int* __restrict__ src_s,
                                int* __restrict__ dst_s, int* __restrict__ eid_s)
{
    int e = blockIdx.x * 256 + threadIdx.x;
    int d = dst[e];
    int p = atomicAdd(&cursor[d], 1);
    src_s[p] = src[e];
    dst_s[p] = d;
    eid_s[p] = e;
}

// ---- Edge kernel: gather -> GEMM1 -> GELU -> hidden-space segment sum ---
// x tile in LDS stored as A-fragment chunks: [kt2][row][8 shorts],
// kt2 = k/8 (0..35). Wave w computes 64 rows x cols [32w, 32w+32).
__global__ __launch_bounds__(256, 4) void edge_kernel(
    const unsigned short* __restrict__ h_bf,
    const int* __restrict__ src_s, const int* __restrict__ dst_s,
    const int* __restrict__ eid_s, const float* __restrict__ ea,
    const short* __restrict__ W1f, const float* __restrict__ pb1,
    float* __restrict__ aggh)
{
    __shared__ __align__(16) short xbuf[36 * 64 * 8];   // 36864 B
    __shared__ int srcl[MT], dstl[MT], eidl[MT];
    float* cbuf = (float*)xbuf;                         // [64][CSTRIDE] overlay (33792 B)

    const int tid = threadIdx.x;
    const long long base = (long long)blockIdx.x * MT;

    if (tid < MT)            srcl[tid]          = src_s[base + tid];
    else if (tid < 2 * MT)   dstl[tid - MT]     = dst_s[base + tid - MT];
    else if (tid < 3 * MT)   eidl[tid - 2 * MT] = eid_s[base + tid - 2 * MT];
    __syncthreads();

    // h part: kt2 0..15 = h[src] cols, 16..31 = h[dst] cols (16B chunks)
    #pragma unroll
    for (int it = 0; it < 8; ++it) {
        int g = it * 256 + tid;
        int kt2 = g >> 6, row = g & 63;
        int node = (kt2 < 16) ? srcl[row] : dstl[row];
        ushort8v v = *(const ushort8v*)(h_bf + (size_t)node * DIM + (kt2 & 15) * 8);
        *(ushort8v*)&xbuf[(kt2 * 64 + row) * 8] = v;
    }
    // ea (kt2 32,33, converted fp32->bf16 here) + zero pad (kt2 34,35)
    {
        int row = (tid & 127) >> 1, hc = tid & 1;
        if (tid < 128) {
            const float4* er = (const float4*)(ea + (size_t)eidl[row] * EDGE_DIM + hc * 8);
            float4 v0 = er[0], v1 = er[1];
            ushort8v o;
            o[0] = f2b(v0.x); o[1] = f2b(v0.y); o[2] = f2b(v0.z); o[3] = f2b(v0.w);
            o[4] = f2b(v1.x); o[5] = f2b(v1.y); o[6] = f2b(v1.z); o[7] = f2b(v1.w);
            *(ushort8v*)&xbuf[((32 + hc) * 64 + row) * 8] = o;
        } else {
            ushort8v z = {0, 0, 0, 0, 0, 0, 0, 0};
            *(ushort8v*)&xbuf[((34 + hc) * 64 + row) * 8] = z;
        }
    }
    __syncthreads();

    const int lane = tid & 63, wave = tid >> 6;
    const int lm = lane & 31, half = lane >> 5;

    // GEMM1: 64 rows x 32 cols per wave, one B load per kt
    floatx16 acc0 = {}, acc1 = {};
    #pragma unroll
    for (int kt = 0; kt < NKT1; ++kt) {
        bf16x8 a0 = *(const bf16x8*)&xbuf[((kt * 2 + half) * 64 + lm) * 8];
        bf16x8 a1 = *(const bf16x8*)&xbuf[((kt * 2 + half) * 64 + 32 + lm) * 8];
        bf16x8 b  = *(const bf16x8*)(W1f + ((kt * 4 + wave) * 64 + lane) * 8);
        acc0 = __builtin_amdgcn_mfma_f32_32x32x16_bf16(a0, b, acc0, 0, 0, 0);
        acc1 = __builtin_amdgcn_mfma_f32_32x32x16_bf16(a1, b, acc1, 0, 0, 0);
    }
    __syncthreads();   // xbuf reads done before cbuf overlay

    // bias + GELU (tanh form) -> fp32 hidden values in cbuf
    float bb = pb1[wave * 32 + lm];
    #pragma unroll
    for (int s = 0; s < 2; ++s) {
        const floatx16& A = s ? acc1 : acc0;
        #pragma unroll
        for (int r = 0; r < 16; ++r) {
            int rr = (r & 3) + 8 * (r >> 2) + 4 * half;
            float v = A[r] + bb;
            float u = v * (1.5957691216f + 0.0713548163f * v * v);
            u = fminf(u, 80.f);
            float t = __expf(u);
            float g = v * t * __builtin_amdgcn_rcpf(t + 1.f);
            cbuf[(s * 32 + rr) * CSTRIDE + wave * 32 + lm] = g;
        }
    }
    __syncthreads();

    // segmented column-sum of hdn, one atomic per (segment, hidden col)
    {
        int col = tid & 127, hf = tid >> 7;
        int r0 = hf * 32, r1 = r0 + 32;
        float s = 0.f;
        int cur = dstl[r0];
        for (int r = r0; r < r1; ++r) {
            s += cbuf[r * CSTRIDE + col];
            int nxt = (r == r1 - 1) ? -1 : dstl[r + 1];
            if (nxt != cur) {
                atomicAdd(&aggh[(size_t)cur * DIM + col], s);
                s = 0.f;
                cur = nxt;
            }
        }
    }
}

// ---- Node kernel: GEMM2 on aggregated hidden + cnt*b2 + residual + LN ---
__global__ __launch_bounds__(256, 4) void node_ln_kernel(
    const float* __restrict__ aggh, const int* __restrict__ counts,
    const short* __restrict__ W2f, const float* __restrict__ pb2,
    const float* __restrict__ h, const float* __restrict__ gamma,
    const float* __restrict__ beta, float* __restrict__ out)
{
    __shared__ __align__(16) float sbuf[64 * CSTRIDE];   // 33792 B (abuf overlay)
    __shared__ int cntl[64];
    short* abuf = (short*)sbuf;                           // first 16384 B

    const int tid = threadIdx.x;
    const int n0 = blockIdx.x * 64;

    if (tid < 64) {
        int node = n0 + tid;
        cntl[tid] = (node < NUM_NODES) ? counts[node] : 0;
    }
    // stage aggh rows -> bf16 A-frag chunks [kt2 0..15][row][8]
    #pragma unroll
    for (int it = 0; it < 4; ++it) {
        int g = it * 256 + tid;
        int kt2 = g >> 6, row = g & 63;
        int node = n0 + row;
        ushort8v o = {0, 0, 0, 0, 0, 0, 0, 0};
        if (node < NUM_NODES) {
            const float4* p = (const float4*)(aggh + (size_t)node * DIM + kt2 * 8);
            float4 v0 = p[0], v1 = p[1];
            o[0] = f2b(v0.x); o[1] = f2b(v0.y); o[2] = f2b(v0.z); o[3] = f2b(v0.w);
            o[4] = f2b(v1.x); o[5] = f2b(v1.y); o[6] = f2b(v1.z); o[7] = f2b(v1.w);
        }
        *(ushort8v*)&abuf[(kt2 * 64 + row) * 8] = o;
    }
    __syncthreads();

    const int lane = tid & 63, wave = tid >> 6;
    const int lm = lane & 31, half = lane >> 5;

    floatx16 acc0 = {}, acc1 = {};
    #pragma unroll
    for (int kt = 0; kt < NKT2; ++kt) {
        bf16x8 a0 = *(const bf16x8*)&abuf[((kt * 2 + half) * 64 + lm) * 8];
        bf16x8 a1 = *(const bf16x8*)&abuf[((kt * 2 + half) * 64 + 32 + lm) * 8];
        bf16x8 b  = *(const bf16x8*)(W2f + ((kt * 4 + wave) * 64 + lane) * 8);
        acc0 = __builtin_amdgcn_mfma_f32_32x32x16_bf16(a0, b, acc0, 0, 0, 0);
        acc1 = __builtin_amdgcn_mfma_f32_32x32x16_bf16(a1, b, acc1, 0, 0, 0);
    }
    __syncthreads();   // abuf reads done before sbuf overlay

    float bb2 = pb2[wave * 32 + lm];
    #pragma unroll
    for (int s = 0; s < 2; ++s) {
        const floatx16& A = s ? acc1 : acc0;
        #pragma unroll
        for (int r = 0; r < 16; ++r) {
            int rr = (r & 3) + 8 * (r >> 2) + 4 * half;
            int row = s * 32 + rr;
            sbuf[row * CSTRIDE + wave * 32 + lm] = A[r] + (float)cntl[row] * bb2;
        }
    }
    __syncthreads();

    // LayerNorm: 4 lanes per row, 32 cols each; rows 16w..16w+15 per wave
    {
        int row = tid >> 2, q = tid & 3;
        int node = n0 + row;
        if (node < NUM_NODES) {
            float4 xv[8];
            float s = 0.f, ss = 0.f;
            const float4* hp = (const float4*)(h + (size_t)node * DIM + q * 32);
            #pragma unroll
            for (int i = 0; i < 8; ++i) {
                float4 c = *(const float4*)&sbuf[row * CSTRIDE + q * 32 + i * 4];
                float4 hh = hp[i];
                float4 x;
                x.x = c.x + hh.x; x.y = c.y + hh.y; x.z = c.z + hh.z; x.w = c.w + hh.w;
                xv[i] = x;
                s  += x.x + x.y + x.z + x.w;
                ss += x.x * x.x + x.y * x.y + x.z * x.z + x.w * x.w;
            }
            s  += __shfl_xor(s, 1, 64);  s  += __shfl_xor(s, 2, 64);
            ss += __shfl_xor(ss, 1, 64); ss += __shfl_xor(ss, 2, 64);
            float mu = s * (1.f / DIM);
            float var = ss * (1.f / DIM) - mu * mu;
            float rs = rsqrtf(var + 1e-5f);
            const float4* gp = (const float4*)(gamma + q * 32);
            const float4* bp = (const float4*)(beta + q * 32);
            float4* op = (float4*)(out + (size_t)node * DIM + q * 32);
            #pragma unroll
            for (int i = 0; i < 8; ++i) {
                float4 g4 = gp[i], b4 = bp[i], o;
                o.x = (xv[i].x - mu) * rs * g4.x + b4.x;
                o.y = (xv[i].y - mu) * rs * g4.y + b4.y;
                o.z = (xv[i].z - mu) * rs * g4.z + b4.z;
                o.w = (xv[i].w - mu) * rs * g4.w + b4.w;
                op[i] = o;
            }
        }
    }
}

extern "C" void kernel_launch(void* const* d_in, const int* in_sizes, int n_in,
                              void* d_out, int out_size, void* d_ws, size_t ws_size,
                              hipStream_t stream)
{
    const float* h     = (const float*)d_in[0];
    const int*   src   = (const int*)d_in[1];
    const int*   dst   = (const int*)d_in[2];
    const float* ea    = (const float*)d_in[3];
    const float* W1    = (const float*)d_in[4];
    const float* pb1   = (const float*)d_in[5];
    const float* W2    = (const float*)d_in[6];
    const float* pb2   = (const float*)d_in[7];
    const float* gamma = (const float*)d_in[8];
    const float* beta  = (const float*)d_in[9];
    float* out = (float*)d_out;

    char* ws = (char*)d_ws;
    short* W1f   = (short*)ws;                        //        0 (73728 B)
    short* W2f   = (short*)(ws + 73728);              //  (32768 B)
    int* counts  = (int*)(ws + 106496);               //  (200000 B)
    int* cursor  = (int*)(ws + 306496);               //  (200000 B)
    int* bsum    = (int*)(ws + 506496);               //  (1024 B)
    int* boffs   = (int*)(ws + 507520);               //  (1024 B)
    int* src_s   = (int*)(ws + 508544);               //  (6400000 B)
    int* dst_s   = (int*)(ws + 6908544);              //  (6400000 B)
    int* eid_s   = (int*)(ws + 13308544);             //  (6400000 B)
    unsigned short* h_bf = (unsigned short*)(ws + 19708544);   // (12800000 B)
    float* aggh  = (float*)(ws + 32508544);           //  (25600000 B) -> 58108544

    hipMemsetAsync(aggh, 0, (size_t)NUM_NODES * DIM * sizeof(float), stream);
    hipMemsetAsync(counts, 0, NUM_NODES * sizeof(int), stream);

    prep_kernel<<<26, 256, 0, stream>>>(W1, W2, W1f, W2f);
    hconv_kernel<<<6250, 256, 0, stream>>>(h, h_bf);
    hist_kernel<<<NUM_EDGES / 256, 256, 0, stream>>>(dst, counts);
    scanA_kernel<<<NSCAN, 256, 0, stream>>>(counts, bsum);
    scanB_kernel<<<1, 256, 0, stream>>>(bsum, boffs);
    scanC_kernel<<<NSCAN, 256, 0, stream>>>(counts, boffs, cursor);
    scatter3_kernel<<<NUM_EDGES / 256, 256, 0, stream>>>(src, dst, cursor,
                                                         src_s, dst_s, eid_s);
    edge_kernel<<<NUM_EDGES / MT, 256, 0, stream>>>(h_bf, src_s, dst_s, eid_s, ea,
                                                    W1f, pb1, aggh);
    node_ln_kernel<<<NODE_BLOCKS, 256, 0, stream>>>(aggh, counts, W2f, pb2,
                                                    h, gamma, beta, out);
}